// Round 7
// baseline (205.910 us; speedup 1.0000x reference)
//
#include <hip/hip_runtime.h>

// DIAGNOSTIC ROUND: single fused kernel, NSPLIT=1, 32 blocks -> runs slow
// (~60us) ON PURPOSE so it beats the 40us harness poison-fills into the
// rocprof top-5 and we finally get VALUBusy / VGPR_Count / LDS_BANK_CONFLICT
// for the real inner loop. Structure otherwise = production candidate:
//   64x64 tile, 4x4/thread, stride-66 conflict-free b64 LDS reads,
//   conflict-free build (lane=ctx, b32 writes), 3.5 ops/pair inner loop.

#define NCTX 1024
#define NG   128
#define NB   8
#define CH   64            // ctx per LDS chunk
#define STR  66            // row stride (words): read banks 2*row mod 32 -> conflict-free b64

__global__ __launch_bounds__(256, 4)
void eds_full(const float* __restrict__ Xc,    // [B][NCTX][2]
              const float* __restrict__ Yc,    // [B][NCTX][2]
              const float* __restrict__ gridp, // [NG*NG][2]
              const float* __restrict__ logl,  // [1]
              float* __restrict__ out)         // [NB][3][NG*NG]
{
    __shared__ float sEx[64 * STR];
    __shared__ float sEy[64 * STR];

    const int tid  = threadIdx.x;
    const int ixl  = tid & 15;
    const int iyl  = tid >> 4;          // 0..15
    const int lane = tid & 63;
    const int wv   = tid >> 6;          // wave 0..3

    const int blk  = blockIdx.x;        // 32 blocks: 8 batches x 4 tiles
    const int tile = blk & 3;
    const int b    = blk >> 2;
    const int tx0  = (tile & 1) * 64;
    const int ty0  = (tile >> 1) * 64;

    const float ls = fminf(5.0f, fmaxf(-5.0f, logl[0]));
    const float l  = expf(ls);
    const float scale = -0.7213475204444817f / (l * l);   // -log2e/2 / l^2

    float d[16], a[16], c[16];
    #pragma unroll
    for (int i = 0; i < 16; ++i) { d[i] = 0.0f; a[i] = 0.0f; c[i] = 0.0f; }

    for (int c0 = 0; c0 < NCTX; c0 += CH) {
        if (c0) __syncthreads();

        // ---- build: lane = ctx index (coalesced X load), wave wv does rows
        // [16wv,16wv+16). LDS writes: addr = row*66 + lane -> banks
        // (2*row+lane)%32, row uniform per instr -> 2-way alias only (free).
        {
            const float2 X = ((const float2*)(Xc + ((size_t)b * NCTX + c0) * 2))[lane];
            #pragma unroll
            for (int r = 0; r < 16; ++r) {
                const int row = wv * 16 + r;
                const float gxr = gridp[2 * (tx0 + row)];             // uniform -> s_load
                const float gyr = gridp[2 * ((ty0 + row) * NG) + 1];  // uniform -> s_load
                const float dx = gxr - X.x;
                const float dy = gyr - X.y;
                sEx[row * STR + lane] = exp2f(dx * dx * scale);
                sEy[row * STR + lane] = exp2f(dy * dy * scale);
            }
        }
        __syncthreads();

        const float4* yp = (const float4*)(Yc + ((size_t)b * NCTX + c0) * 2);
        const float* exb = &sEx[ixl * STR];
        const float* eyb = &sEy[iyl * STR];

        #pragma unroll 2
        for (int k = 0; k < CH / 2; ++k) {        // 2 ctx per step
            float2 ex[4], ey[4];
            #pragma unroll
            for (int i = 0; i < 4; ++i) ex[i] = *(const float2*)&exb[16 * i * STR + 2 * k];
            #pragma unroll
            for (int j = 0; j < 4; ++j) ey[j] = *(const float2*)&eyb[16 * j * STR + 2 * k];
            const float4 y = yp[k];               // (y1,y2)[2k], (y1,y2)[2k+1]

            // precompute ey*y per j (amortized over i=4): 3.5 ops/pair
            float e1a[4], e2a[4], e1b[4], e2b[4];
            #pragma unroll
            for (int j = 0; j < 4; ++j) {
                e1a[j] = ey[j].x * y.x;  e2a[j] = ey[j].x * y.y;
                e1b[j] = ey[j].y * y.z;  e2b[j] = ey[j].y * y.w;
            }
            #pragma unroll
            for (int i = 0; i < 4; ++i) {
                #pragma unroll
                for (int j = 0; j < 4; ++j) {
                    const int o = i * 4 + j;
                    d[o] = fmaf(ex[i].x, ey[j].x, d[o]);
                    a[o] = fmaf(ex[i].x, e1a[j], a[o]);
                    c[o] = fmaf(ex[i].x, e2a[j], c[o]);
                    d[o] = fmaf(ex[i].y, ey[j].y, d[o]);
                    a[o] = fmaf(ex[i].y, e1b[j], a[o]);
                    c[o] = fmaf(ex[i].y, e2b[j], c[o]);
                }
            }
        }
    }

    // ---- epilogue: divide + direct store (no workspace, no combine kernel)
    const size_t G = (size_t)NG * NG;
    float* O = out + (size_t)b * 3 * G;
    #pragma unroll
    for (int i = 0; i < 4; ++i) {
        #pragma unroll
        for (int j = 0; j < 4; ++j) {
            const int o = (ty0 + iyl + 16 * j) * NG + (tx0 + ixl + 16 * i);
            const int t = i * 4 + j;
            O[        o] = d[t];
            O[G     + o] = a[t] / d[t];
            O[2 * G + o] = c[t] / d[t];
        }
    }
}

extern "C" void kernel_launch(void* const* d_in, const int* in_sizes, int n_in,
                              void* d_out, int out_size, void* d_ws, size_t ws_size,
                              hipStream_t stream) {
    const float* Xc = (const float*)d_in[0];
    const float* Yc = (const float*)d_in[1];
    const float* gr = (const float*)d_in[2];
    const float* ll = (const float*)d_in[3];
    float* out = (float*)d_out;

    eds_full<<<dim3(NB * 4), dim3(256), 0, stream>>>(Xc, Yc, gr, ll, out);
}

// Round 10
// 104.403 us; speedup vs baseline: 1.9723x; 1.9723x over previous
//
#include <hip/hip_runtime.h>

// EquivDeepSet: out[b][c][iy][ix], c = {density, f1, f2}
// Separable Gaussian: Gram = exp2(s*dx^2)*exp2(s*dy^2), s = -log2e/(2 l^2).
// r7 diagnostic found the real stall: global y-loads + unpipelined LDS reads
// in the inner loop (42% per-SIMD busy at 1 wave). This version:
//  - Y staged in LDS at build time (uniform-addr reads = broadcast, free)
//  - explicit 2-stage A/B software pipeline (loads for k+1 issued before
//    FMAs of k; all indices compile-time static)
//  - 4 ctx/step via b128 LDS reads (stride 66: 2-way alias only = free)
//  - 64x64 tile, 4x4/thread, 3.5 ops/pair, NSPLIT=16 (512 blocks, 2/CU)

#define NCTX 1024
#define NG   128
#define NB   8
#define CH   64            // ctx per split
#define STR  66            // LDS row stride (words) -> conflict-free reads
#define NSPLIT 16

__device__ __forceinline__ void ctx1(float ex0, float ex1, float ex2, float ex3,
                                     float ey0, float ey1, float ey2, float ey3,
                                     float y1, float y2,
                                     float (&d)[16], float (&a)[16], float (&c)[16])
{
    const float exv[4] = {ex0, ex1, ex2, ex3};
    const float eyv[4] = {ey0, ey1, ey2, ey3};
    float e1[4], e2[4];
    #pragma unroll
    for (int j = 0; j < 4; ++j) { e1[j] = eyv[j] * y1; e2[j] = eyv[j] * y2; }
    #pragma unroll
    for (int i = 0; i < 4; ++i) {
        #pragma unroll
        for (int j = 0; j < 4; ++j) {
            const int o = i * 4 + j;
            d[o] = fmaf(exv[i], eyv[j], d[o]);
            a[o] = fmaf(exv[i], e1[j], a[o]);
            c[o] = fmaf(exv[i], e2[j], c[o]);
        }
    }
}

__device__ __forceinline__ void step4(const float4 (&ex)[4], const float4 (&ey)[4],
                                      float4 ya, float4 yb,
                                      float (&d)[16], float (&a)[16], float (&c)[16])
{
    ctx1(ex[0].x, ex[1].x, ex[2].x, ex[3].x, ey[0].x, ey[1].x, ey[2].x, ey[3].x, ya.x, ya.y, d, a, c);
    ctx1(ex[0].y, ex[1].y, ex[2].y, ex[3].y, ey[0].y, ey[1].y, ey[2].y, ey[3].y, ya.z, ya.w, d, a, c);
    ctx1(ex[0].z, ex[1].z, ex[2].z, ex[3].z, ey[0].z, ey[1].z, ey[2].z, ey[3].z, yb.x, yb.y, d, a, c);
    ctx1(ex[0].w, ex[1].w, ex[2].w, ex[3].w, ey[0].w, ey[1].w, ey[2].w, ey[3].w, yb.z, yb.w, d, a, c);
}

__global__ __launch_bounds__(256, 2)
void eds_partial(const float* __restrict__ Xc,    // [B][NCTX][2]
                 const float* __restrict__ Yc,    // [B][NCTX][2]
                 const float* __restrict__ gridp, // [NG*NG][2]
                 const float* __restrict__ logl,  // [1]
                 float* __restrict__ part)        // [NSPLIT][NB][3][NG*NG]
{
    __shared__ float sEx[64 * STR];
    __shared__ float sEy[64 * STR];
    __shared__ float sY[2 * CH + 8];    // (y1,y2) pairs + pad for pipeline overread

    const int tid  = threadIdx.x;
    const int ixl  = tid & 15;
    const int iyl  = tid >> 4;          // 0..15
    const int lane = tid & 63;
    const int wv   = tid >> 6;          // wave 0..3

    int blk = blockIdx.x;
    const int s    = blk & (NSPLIT - 1);  blk >>= 4;
    const int tile = blk & 3;           // 2x2 tiles of 64x64
    const int b    = blk >> 2;
    const int tx0  = (tile & 1) * 64;
    const int ty0  = (tile >> 1) * 64;

    const float ls = fminf(5.0f, fmaxf(-5.0f, logl[0]));
    const float l  = expf(ls);
    const float scale = -0.7213475204444817f / (l * l);   // -log2e/2 / l^2

    const int cb = s * CH;              // this block's ctx slice

    // ---- build: lane = ctx (coalesced X loads), wave wv does rows [16wv,16wv+16)
    // LDS writes at row*66+lane: banks (2row+lane)%32 -> 2-way alias only (free).
    {
        const float2 X = ((const float2*)(Xc + ((size_t)b * NCTX + cb) * 2))[lane];
        #pragma unroll
        for (int r = 0; r < 16; ++r) {
            const int row = wv * 16 + r;
            const float gxr = gridp[2 * (tx0 + row)];             // uniform -> s_load
            const float gyr = gridp[2 * ((ty0 + row) * NG) + 1];  // uniform -> s_load
            const float dx = gxr - X.x;
            const float dy = gyr - X.y;
            sEx[row * STR + lane] = exp2f(dx * dx * scale);
            sEy[row * STR + lane] = exp2f(dy * dy * scale);
        }
        if (wv == 0) {                  // stage Y: kills global latency in loop
            const float2 yv = ((const float2*)(Yc + ((size_t)b * NCTX + cb) * 2))[lane];
            *(float2*)&sY[2 * lane] = yv;
        }
    }
    __syncthreads();

    float d[16], a[16], c[16];
    #pragma unroll
    for (int i = 0; i < 16; ++i) { d[i] = 0.0f; a[i] = 0.0f; c[i] = 0.0f; }

    const float*  exb = &sEx[ixl * STR];
    const float*  eyb = &sEy[iyl * STR];
    const float4* y4  = (const float4*)sY;

#define LOADS(EX, EY, YA, YB, K)                                          \
    { const int k_ = (K) & 15;                                            \
      EX[0] = *(const float4*)&exb[ 0 * STR + 4 * k_];                    \
      EX[1] = *(const float4*)&exb[16 * STR + 4 * k_];                    \
      EX[2] = *(const float4*)&exb[32 * STR + 4 * k_];                    \
      EX[3] = *(const float4*)&exb[48 * STR + 4 * k_];                    \
      EY[0] = *(const float4*)&eyb[ 0 * STR + 4 * k_];                    \
      EY[1] = *(const float4*)&eyb[16 * STR + 4 * k_];                    \
      EY[2] = *(const float4*)&eyb[32 * STR + 4 * k_];                    \
      EY[3] = *(const float4*)&eyb[48 * STR + 4 * k_];                    \
      YA = y4[2 * k_];  YB = y4[2 * k_ + 1]; }

    // explicit 2-stage pipeline: loads for step k+1 issue before FMAs of k
    float4 exA[4], eyA[4], yaA, ybA;
    float4 exB[4], eyB[4], yaB, ybB;
    LOADS(exA, eyA, yaA, ybA, 0)
    #pragma unroll
    for (int kk = 0; kk < 8; ++kk) {
        LOADS(exB, eyB, yaB, ybB, 2 * kk + 1)
        step4(exA, eyA, yaA, ybA, d, a, c);
        LOADS(exA, eyA, yaA, ybA, 2 * kk + 2)   // kk=7 wraps to 0 (harmless)
        step4(exB, eyB, yaB, ybB, d, a, c);
    }
#undef LOADS

    const size_t G = (size_t)NG * NG;
    float* P = part + ((size_t)(s * NB + b) * 3) * G;
    #pragma unroll
    for (int i = 0; i < 4; ++i) {
        #pragma unroll
        for (int j = 0; j < 4; ++j) {
            const int o = (ty0 + iyl + 16 * j) * NG + (tx0 + ixl + 16 * i);
            P[        o] = d[i * 4 + j];
            P[G     + o] = a[i * 4 + j];
            P[2 * G + o] = c[i * 4 + j];
        }
    }
}

__global__ __launch_bounds__(256)
void eds_combine(const float* __restrict__ part, float* __restrict__ out)
{
    const size_t G = (size_t)NG * NG;
    const int t = blockIdx.x * 256 + threadIdx.x;   // NB*G/4 threads
    const int b  = t >> 12;                         // 4096 float4 per batch
    const int o4 = t & 4095;
    float4 dd = make_float4(0.f, 0.f, 0.f, 0.f);
    float4 a1 = dd, a2 = dd;
    #pragma unroll
    for (int ss = 0; ss < NSPLIT; ++ss) {
        const float4* P = (const float4*)(part + ((size_t)(ss * NB + b) * 3) * G);
        const float4 pd = P[o4];
        const float4 p1 = P[G / 4 + o4];
        const float4 p2 = P[G / 2 + o4];
        dd.x += pd.x; dd.y += pd.y; dd.z += pd.z; dd.w += pd.w;
        a1.x += p1.x; a1.y += p1.y; a1.z += p1.z; a1.w += p1.w;
        a2.x += p2.x; a2.y += p2.y; a2.z += p2.z; a2.w += p2.w;
    }
    float4* O = (float4*)(out + (size_t)b * 3 * G);
    O[o4] = dd;
    O[G / 4 + o4] = make_float4(a1.x / dd.x, a1.y / dd.y, a1.z / dd.z, a1.w / dd.w);
    O[G / 2 + o4] = make_float4(a2.x / dd.x, a2.y / dd.y, a2.z / dd.z, a2.w / dd.w);
}

extern "C" void kernel_launch(void* const* d_in, const int* in_sizes, int n_in,
                              void* d_out, int out_size, void* d_ws, size_t ws_size,
                              hipStream_t stream) {
    const float* Xc = (const float*)d_in[0];
    const float* Yc = (const float*)d_in[1];
    const float* gr = (const float*)d_in[2];
    const float* ll = (const float*)d_in[3];
    float* out  = (float*)d_out;
    float* part = (float*)d_ws;

    eds_partial<<<dim3(NB * 4 * NSPLIT), dim3(256), 0, stream>>>(Xc, Yc, gr, ll, part);
    eds_combine<<<dim3(NB * NG * NG / 4 / 256), dim3(256), 0, stream>>>(part, out);
}

// Round 12
// 86.034 us; speedup vs baseline: 2.3934x; 1.2135x over previous
//
#include <hip/hip_runtime.h>

// EquivDeepSet: out[b][c][iy][ix], c = {density, f1, f2}
// Separable Gaussian: Gram = exp2(s*dx^2)*exp2(s*dy^2), s = -log2e/(2 l^2).
// r10 counters (partial=43us, VALUBusy 28%, VGPR=64, conflicts=0) diagnosed:
//  (1) STR=66 made odd-ixl rows 8B-misaligned -> no ds_read_b128 possible;
//  (2) allocator picked 64 VGPR for a ~110-reg working set -> loads serialized
//      through a tiny register window (s_waitcnt chains), pipeline dead.
// Fixes: STR=68 (rows 272B = 16-byte aligned; banks (4row)%32 -> 2-way = free)
// and uncapped __launch_bounds__(256) so the A/B pipeline stays in registers.

#define NCTX 1024
#define NG   128
#define NB   8
#define CH   64            // ctx per split
#define STR  68            // row stride (words): 272B rows -> 16B-aligned b128
#define NSPLIT 16

__device__ __forceinline__ void ctx1(float ex0, float ex1, float ex2, float ex3,
                                     float ey0, float ey1, float ey2, float ey3,
                                     float y1, float y2,
                                     float (&d)[16], float (&a)[16], float (&c)[16])
{
    const float exv[4] = {ex0, ex1, ex2, ex3};
    const float eyv[4] = {ey0, ey1, ey2, ey3};
    float e1[4], e2[4];
    #pragma unroll
    for (int j = 0; j < 4; ++j) { e1[j] = eyv[j] * y1; e2[j] = eyv[j] * y2; }
    #pragma unroll
    for (int i = 0; i < 4; ++i) {
        #pragma unroll
        for (int j = 0; j < 4; ++j) {
            const int o = i * 4 + j;
            d[o] = fmaf(exv[i], eyv[j], d[o]);
            a[o] = fmaf(exv[i], e1[j], a[o]);
            c[o] = fmaf(exv[i], e2[j], c[o]);
        }
    }
}

__device__ __forceinline__ void step4(const float4 (&ex)[4], const float4 (&ey)[4],
                                      float4 ya, float4 yb,
                                      float (&d)[16], float (&a)[16], float (&c)[16])
{
    ctx1(ex[0].x, ex[1].x, ex[2].x, ex[3].x, ey[0].x, ey[1].x, ey[2].x, ey[3].x, ya.x, ya.y, d, a, c);
    ctx1(ex[0].y, ex[1].y, ex[2].y, ex[3].y, ey[0].y, ey[1].y, ey[2].y, ey[3].y, ya.z, ya.w, d, a, c);
    ctx1(ex[0].z, ex[1].z, ex[2].z, ex[3].z, ey[0].z, ey[1].z, ey[2].z, ey[3].z, yb.x, yb.y, d, a, c);
    ctx1(ex[0].w, ex[1].w, ex[2].w, ex[3].w, ey[0].w, ey[1].w, ey[2].w, ey[3].w, yb.z, yb.w, d, a, c);
}

__global__ __launch_bounds__(256)
void eds_partial(const float* __restrict__ Xc,    // [B][NCTX][2]
                 const float* __restrict__ Yc,    // [B][NCTX][2]
                 const float* __restrict__ gridp, // [NG*NG][2]
                 const float* __restrict__ logl,  // [1]
                 float* __restrict__ part)        // [NSPLIT][NB][3][NG*NG]
{
    __shared__ float sEx[64 * STR];
    __shared__ float sEy[64 * STR];
    __shared__ float sY[2 * CH + 8];    // (y1,y2) pairs + pad for pipeline overread

    const int tid  = threadIdx.x;
    const int ixl  = tid & 15;
    const int iyl  = tid >> 4;          // 0..15
    const int lane = tid & 63;
    const int wv   = tid >> 6;          // wave 0..3

    int blk = blockIdx.x;
    const int s    = blk & (NSPLIT - 1);  blk >>= 4;
    const int tile = blk & 3;           // 2x2 tiles of 64x64
    const int b    = blk >> 2;
    const int tx0  = (tile & 1) * 64;
    const int ty0  = (tile >> 1) * 64;

    const float ls = fminf(5.0f, fmaxf(-5.0f, logl[0]));
    const float l  = expf(ls);
    const float scale = -0.7213475204444817f / (l * l);   // -log2e/2 / l^2

    const int cb = s * CH;              // this block's ctx slice

    // ---- build: lane = ctx (coalesced X loads), wave wv does rows [16wv,16wv+16)
    // LDS writes at row*68+lane: banks (4row+lane)%32 -> 2-way alias only (free).
    {
        const float2 X = ((const float2*)(Xc + ((size_t)b * NCTX + cb) * 2))[lane];
        #pragma unroll
        for (int r = 0; r < 16; ++r) {
            const int row = wv * 16 + r;
            const float gxr = gridp[2 * (tx0 + row)];             // uniform -> s_load
            const float gyr = gridp[2 * ((ty0 + row) * NG) + 1];  // uniform -> s_load
            const float dx = gxr - X.x;
            const float dy = gyr - X.y;
            sEx[row * STR + lane] = exp2f(dx * dx * scale);
            sEy[row * STR + lane] = exp2f(dy * dy * scale);
        }
        if (wv == 0) {                  // stage Y: kills global latency in loop
            const float2 yv = ((const float2*)(Yc + ((size_t)b * NCTX + cb) * 2))[lane];
            *(float2*)&sY[2 * lane] = yv;
        }
    }
    __syncthreads();

    float d[16], a[16], c[16];
    #pragma unroll
    for (int i = 0; i < 16; ++i) { d[i] = 0.0f; a[i] = 0.0f; c[i] = 0.0f; }

    const float*  exb = &sEx[ixl * STR];   // 272-byte row stride: 16B-aligned
    const float*  eyb = &sEy[iyl * STR];
    const float4* y4  = (const float4*)sY;

#define LOADS(EX, EY, YA, YB, K)                                          \
    { const int k_ = (K) & 15;                                            \
      EX[0] = *(const float4*)&exb[ 0 * STR + 4 * k_];                    \
      EX[1] = *(const float4*)&exb[16 * STR + 4 * k_];                    \
      EX[2] = *(const float4*)&exb[32 * STR + 4 * k_];                    \
      EX[3] = *(const float4*)&exb[48 * STR + 4 * k_];                    \
      EY[0] = *(const float4*)&eyb[ 0 * STR + 4 * k_];                    \
      EY[1] = *(const float4*)&eyb[16 * STR + 4 * k_];                    \
      EY[2] = *(const float4*)&eyb[32 * STR + 4 * k_];                    \
      EY[3] = *(const float4*)&eyb[48 * STR + 4 * k_];                    \
      YA = y4[2 * k_];  YB = y4[2 * k_ + 1]; }

    // explicit 2-stage pipeline: loads for step k+1 issue before FMAs of k
    float4 exA[4], eyA[4], yaA, ybA;
    float4 exB[4], eyB[4], yaB, ybB;
    LOADS(exA, eyA, yaA, ybA, 0)
    #pragma unroll
    for (int kk = 0; kk < 8; ++kk) {
        LOADS(exB, eyB, yaB, ybB, 2 * kk + 1)
        step4(exA, eyA, yaA, ybA, d, a, c);
        LOADS(exA, eyA, yaA, ybA, 2 * kk + 2)   // kk=7 wraps to 0 (harmless)
        step4(exB, eyB, yaB, ybB, d, a, c);
    }
#undef LOADS

    const size_t G = (size_t)NG * NG;
    float* P = part + ((size_t)(s * NB + b) * 3) * G;
    #pragma unroll
    for (int i = 0; i < 4; ++i) {
        #pragma unroll
        for (int j = 0; j < 4; ++j) {
            const int o = (ty0 + iyl + 16 * j) * NG + (tx0 + ixl + 16 * i);
            P[        o] = d[i * 4 + j];
            P[G     + o] = a[i * 4 + j];
            P[2 * G + o] = c[i * 4 + j];
        }
    }
}

__global__ __launch_bounds__(256)
void eds_combine(const float* __restrict__ part, float* __restrict__ out)
{
    const size_t G = (size_t)NG * NG;
    const int t = blockIdx.x * 256 + threadIdx.x;   // NB*G/4 threads
    const int b  = t >> 12;                         // 4096 float4 per batch
    const int o4 = t & 4095;
    float4 dd = make_float4(0.f, 0.f, 0.f, 0.f);
    float4 a1 = dd, a2 = dd;
    #pragma unroll
    for (int ss = 0; ss < NSPLIT; ++ss) {
        const float4* P = (const float4*)(part + ((size_t)(ss * NB + b) * 3) * G);
        const float4 pd = P[o4];
        const float4 p1 = P[G / 4 + o4];
        const float4 p2 = P[G / 2 + o4];
        dd.x += pd.x; dd.y += pd.y; dd.z += pd.z; dd.w += pd.w;
        a1.x += p1.x; a1.y += p1.y; a1.z += p1.z; a1.w += p1.w;
        a2.x += p2.x; a2.y += p2.y; a2.z += p2.z; a2.w += p2.w;
    }
    float4* O = (float4*)(out + (size_t)b * 3 * G);
    O[o4] = dd;
    O[G / 4 + o4] = make_float4(a1.x / dd.x, a1.y / dd.y, a1.z / dd.z, a1.w / dd.w);
    O[G / 2 + o4] = make_float4(a2.x / dd.x, a2.y / dd.y, a2.z / dd.z, a2.w / dd.w);
}

extern "C" void kernel_launch(void* const* d_in, const int* in_sizes, int n_in,
                              void* d_out, int out_size, void* d_ws, size_t ws_size,
                              hipStream_t stream) {
    const float* Xc = (const float*)d_in[0];
    const float* Yc = (const float*)d_in[1];
    const float* gr = (const float*)d_in[2];
    const float* ll = (const float*)d_in[3];
    float* out  = (float*)d_out;
    float* part = (float*)d_ws;

    eds_partial<<<dim3(NB * 4 * NSPLIT), dim3(256), 0, stream>>>(Xc, Yc, gr, ll, part);
    eds_combine<<<dim3(NB * NG * NG / 4 / 256), dim3(256), 0, stream>>>(part, out);
}